// Round 32
// baseline (133.126 us; speedup 1.0000x reference)
//
#include <hip/hip_runtime.h>

#define NB 8192
#define NT 365
#define NF 5
#define NH 10
#define NG 40
#define GPW 4    // 4 batch elements per wave, 16-lane groups (u<10 active)
#define GSTR 168            // LDS group stride (floats); pad absorbs u=10..15
#define ASTR (4 * GSTR)
#define WSTR (2 * ASTR)

typedef float f2 __attribute__((ext_vector_type(2)));

// r31 base (117us): identity-W_hh fast path (verified at startup, general
// r27 fallback), 2048 waves uniform 2/SIMD, x in 8-step register chunks,
// LDS-staged h/c with 16-step coalesced burst drains.
//
// NEW vs r31 (issue cuts; wall ~384cyc/SIMD-step ~= 2x ~170cyc/wave issue
// of which ~80 is trans-issue):
//  * exp2 fold: -log2e (x2 for g-gate) baked into W_ih/bias/h-coeff ->
//    exp2f() direct, deleting 4 muls/step.
//  * gate accumulators as float2 pairs via __builtin_elementwise_fma ->
//    v_pk_fma_f32 (full-rate packed fp32): 24 FMA -> 12 pk ops.
//  * LDS staging writes unguarded (dead lanes hit the pad, never drained).
__global__ __launch_bounds__(512, 2)
void lstm_idp(const float* __restrict__ x,
              const float* __restrict__ w_ih,
              const float* __restrict__ w_hh,
              const float* __restrict__ bias,
              const float* __restrict__ fc_w,
              const float* __restrict__ fc_b,
              float* __restrict__ out)
{
    __shared__ float sbuf[8 * WSTR];   // 43,008 B

    const int tid  = threadIdx.x;
    const int lane = tid & 63;
    const int wv   = tid >> 6;
    const int wid  = (blockIdx.x * 512 + tid) >> 6;
    const int g    = lane >> 4;
    const int u    = lane & 15;
    const bool alive = (u < NH);
    const int  uc   = alive ? u : 0;
    const long b    = (long)wid * GPW + g;

    float* h_out = out + NB;
    float* c_out = h_out + (size_t)NB * NT * NH;

    const float L2E = 1.4426950408889634f;

    // ---- weights + identity check ----
    float wih[NF][4], whh[NH][4], bq[4];
    bool idok = true;
    #pragma unroll
    for (int q = 0; q < 4; ++q) {
        const float gs = (q == 3) ? 2.0f : 1.0f;
        const int col = q * NH + uc;
        #pragma unroll
        for (int f = 0; f < NF; ++f) wih[f][q] = w_ih[f * NG + col] * gs;
        #pragma unroll
        for (int j = 0; j < NH; ++j) {
            const float w = w_hh[j * NG + col];
            whh[j][q] = w * gs;
            idok = idok && (w == ((j == uc) ? 1.0f : 0.0f));
        }
        bq[q] = bias[col] * gs;
    }
    const bool isI = (__all((int)idok) != 0);

    // folded fast-path weights: r' = -log2e * r accumulated directly
    f2 wp[NF], wq[NF], bp, bpq;
    #pragma unroll
    for (int f = 0; f < NF; ++f) {
        wp[f] = (f2){-L2E * wih[f][0], -L2E * wih[f][1]};
        wq[f] = (f2){-L2E * wih[f][2], -L2E * wih[f][3]};  // wih[f][3] has gs=2
    }
    bp  = (f2){-L2E * bq[0], -L2E * bq[1]};
    bpq = (f2){-L2E * bq[2], -L2E * bq[3]};
    const f2 HC01 = (f2){-L2E, -L2E};
    const f2 HC23 = (f2){-L2E, -2.0f * L2E};

    int aj[NH];
    #pragma unroll
    for (int j = 0; j < NH; ++j) aj[j] = ((lane & 48) + j) * 4;

    float hAll[NH];
    #pragma unroll
    for (int j = 0; j < NH; ++j) hAll[j] = 0.f;
    float c = 0.f, hS = 0.f;

    const float* xp = x + (size_t)b * NT * NF;

    float* Lw = &sbuf[wv * WSTR];
    float* wh = Lw + g * GSTR + u;       // u up to 15 lands in pad (<GSTR)
    float* wc = wh + ASTR;

    float A[40], B[40];

#define LD8(dst, t0) { \
    const float4* p4 = reinterpret_cast<const float4*>(xp + (size_t)(t0) * NF); \
    _Pragma("unroll") \
    for (int i = 0; i < 10; ++i) { \
        float4 v = p4[i]; \
        dst[i*4+0] = v.x; dst[i*4+1] = v.y; dst[i*4+2] = v.z; dst[i*4+3] = v.w; } }

#define LDT(dst) { \
    const float4* p4 = reinterpret_cast<const float4*>(xp + (size_t)360 * NF); \
    _Pragma("unroll") \
    for (int i = 0; i < 6; ++i) { \
        float4 v = p4[i]; \
        dst[i*4+0] = v.x; dst[i*4+1] = v.y; dst[i*4+2] = v.z; dst[i*4+3] = v.w; } \
    dst[24] = xp[360 * NF + 24]; }

// fast-step core, exp2-folded, pk-fma pairs
#define CORE(buf, s) \
    f2 r01 = bp, r23 = bpq; \
    _Pragma("unroll") \
    for (int f = 0; f < NF; ++f) { \
        const float xv = buf[(s) * NF + f]; \
        const f2 xv2 = (f2){xv, xv}; \
        r01 = __builtin_elementwise_fma(xv2, wp[f], r01); \
        r23 = __builtin_elementwise_fma(xv2, wq[f], r23); } \
    { const f2 hs2 = (f2){hS, hS}; \
      r01 = __builtin_elementwise_fma(hs2, HC01, r01); \
      r23 = __builtin_elementwise_fma(hs2, HC23, r23); } \
    const float sf = __builtin_amdgcn_rcpf(1.0f + exp2f(r01.x)); \
    const float si = __builtin_amdgcn_rcpf(1.0f + exp2f(r01.y)); \
    const float so = __builtin_amdgcn_rcpf(1.0f + exp2f(r23.x)); \
    const float tg = fmaf(2.0f, __builtin_amdgcn_rcpf(1.0f + exp2f(r23.y)), -1.0f); \
    c = fmaf(sf, c, si * tg); \
    const float th = fmaf(2.0f, \
        __builtin_amdgcn_rcpf(1.0f + exp2f(-2.8853900817779268f * c)), -1.0f); \
    hS = so * th;

#define STEPI(buf, s, slot) { \
    CORE(buf, s) \
    wh[(slot) * NH] = hS; wc[(slot) * NH] = c; }

#define STEPD(buf, s) { \
    CORE(buf, s) \
    if (alive) { hcp[(s) * NH] = hS; ccp[(s) * NH] = c; } }

#define RUN8I(buf, s0) { STEPI(buf,0,(s0)+0) STEPI(buf,1,(s0)+1) \
    STEPI(buf,2,(s0)+2) STEPI(buf,3,(s0)+3) STEPI(buf,4,(s0)+4) \
    STEPI(buf,5,(s0)+5) STEPI(buf,6,(s0)+6) STEPI(buf,7,(s0)+7) }

#define BURST(t0) { \
    _Pragma("unroll") \
    for (int i = 0; i < 10; ++i) { \
        const int c0   = i * 64; \
        const int run0 = c0 / 80; \
        const int lb   = (run0 + 1) * 80 - c0; \
        const int run  = (lane < lb) ? run0 : run0 + 1; \
        const int arr  = run >> 2; \
        const int g_   = run & 3; \
        const int off2 = c0 + lane - run * 80; \
        const float* ls = Lw + arr * ASTR + g_ * GSTR + off2 * 2; \
        float2 v; v.x = ls[0]; v.y = ls[1]; \
        float* gp = (arr ? c_out : h_out) \
                    + ((size_t)wid * GPW + g_) * (NT * NH) \
                    + (size_t)(t0) * NH + off2 * 2; \
        *reinterpret_cast<float2*>(gp) = v; } }

// general fallback (r27 verbatim, unfolded weights)
#define STEPG(buf, s) { \
    float r0 = bq[0], r1 = bq[1], r2 = bq[2], r3 = bq[3]; \
    _Pragma("unroll") \
    for (int f = 0; f < NF; ++f) { \
        const float xv = buf[(s) * NF + f]; \
        r0 = fmaf(xv, wih[f][0], r0); r1 = fmaf(xv, wih[f][1], r1); \
        r2 = fmaf(xv, wih[f][2], r2); r3 = fmaf(xv, wih[f][3], r3); } \
    _Pragma("unroll") \
    for (int j = 0; j < NH; ++j) { \
        const float hv = hAll[j]; \
        r0 = fmaf(hv, whh[j][0], r0); r1 = fmaf(hv, whh[j][1], r1); \
        r2 = fmaf(hv, whh[j][2], r2); r3 = fmaf(hv, whh[j][3], r3); } \
    const float sf = __builtin_amdgcn_rcpf(1.0f + __expf(-r0)); \
    const float si = __builtin_amdgcn_rcpf(1.0f + __expf(-r1)); \
    const float so = __builtin_amdgcn_rcpf(1.0f + __expf(-r2)); \
    const float tg = fmaf(2.0f, __builtin_amdgcn_rcpf(1.0f + __expf(-r3)), -1.0f); \
    c = fmaf(sf, c, si * tg); \
    const float th = fmaf(2.0f, __builtin_amdgcn_rcpf(1.0f + __expf(-2.0f * c)), -1.0f); \
    const float h = so * th; \
    _Pragma("unroll") \
    for (int j = 0; j < NH; ++j) \
        hAll[j] = __int_as_float(__builtin_amdgcn_ds_bpermute(aj[j], __float_as_int(h))); \
    if (alive) { hcp[(s) * NH] = h; ccp[(s) * NH] = c; } }

#define RUN8G(buf) { STEPG(buf,0) STEPG(buf,1) STEPG(buf,2) STEPG(buf,3) \
                     STEPG(buf,4) STEPG(buf,5) STEPG(buf,6) STEPG(buf,7) \
                     hcp += 8 * NH; ccp += 8 * NH; }

    if (isI) {
        LD8(A, 0)
        for (int cc = 0; cc < 22; ++cc) {        // t = 0..351
            const int t0 = cc * 16;
            LD8(B, t0 + 8)
            RUN8I(A, 0)
            LD8(A, t0 + 16)
            RUN8I(B, 8)
            BURST(t0)
        }
        float* hcp = h_out + (size_t)b * NT * NH + 352 * NH + uc;
        float* ccp = c_out + (size_t)b * NT * NH + 352 * NH + uc;
        LDT(B)
        { STEPD(A,0) STEPD(A,1) STEPD(A,2) STEPD(A,3)
          STEPD(A,4) STEPD(A,5) STEPD(A,6) STEPD(A,7) }
        hcp += 8 * NH; ccp += 8 * NH;
        { STEPD(B,0) STEPD(B,1) STEPD(B,2) STEPD(B,3) STEPD(B,4) }
        #pragma unroll
        for (int j = 0; j < NH; ++j)
            hAll[j] = __int_as_float(
                __builtin_amdgcn_ds_bpermute(aj[j], __float_as_int(hS)));
    } else {
        float* hcp = h_out + (size_t)b * NT * NH + uc;
        float* ccp = c_out + (size_t)b * NT * NH + uc;
        LD8(A, 0)
        for (int cc = 0; cc < 22; ++cc) {
            const int t0 = cc * 16;
            LD8(B, t0 + 8)
            RUN8G(A)
            LD8(A, t0 + 16)
            RUN8G(B)
        }
        LDT(B)
        RUN8G(A)
        { STEPG(B,0) STEPG(B,1) STEPG(B,2) STEPG(B,3) STEPG(B,4) }
    }

    if (u == 0) {
        float acc = fc_b[0];
        #pragma unroll
        for (int j = 0; j < NH; ++j) acc = fmaf(hAll[j], fc_w[j], acc);
        out[b] = acc;
    }
}

extern "C" void kernel_launch(void* const* d_in, const int* in_sizes, int n_in,
                              void* d_out, int out_size, void* d_ws, size_t ws_size,
                              hipStream_t stream) {
    const float* x    = (const float*)d_in[0];
    const float* wih  = (const float*)d_in[1];
    const float* whh  = (const float*)d_in[2];
    const float* bias = (const float*)d_in[3];
    const float* fcw  = (const float*)d_in[4];
    const float* fcb  = (const float*)d_in[5];
    float* out = (float*)d_out;

    lstm_idp<<<256, 512, 0, stream>>>(x, wih, whh, bias, fcw, fcb, out);
}